// Round 1
// baseline (276.560 us; speedup 1.0000x reference)
//
#include <hip/hip_runtime.h>

#define HH 256
#define WW 256
#define PLANE (HH*WW)
#define TILE_R 32
#define TILE_C 64
#define TT 8
#define ER (TILE_R + 2*TT)   // 48 ext rows
#define EC (TILE_C + 2*TT)   // 80 ext cols
#define NCP (EC/2)           // 40 col-pairs
#define NRG 6                // row groups
#define RPT (ER/NRG)         // 8 rows per thread

// horizontal [1,2,1] sums for the thread's two columns; also returns center pair
__device__ __forceinline__ float2 hrow(const float* p, int o0, int ob, int o2, float2* cen) {
    float2 a = *(const float2*)(p + o0);
    float2 b = *(const float2*)(p + ob);
    float2 c = *(const float2*)(p + o2);
    *cen = b;
    return make_float2(fmaf(2.f, b.x, a.y) + b.y,
                       fmaf(2.f, b.y, b.x) + c.x);
}

__global__ __launch_bounds__(256, 1)
void hs_phase(const float* __restrict__ x,     // (8,3,256,256): It, Ix, Iy
              const float* __restrict__ src,   // (8,2,256,256): u, v
              float* __restrict__ dst,         // (8,2,256,256)
              int niter)
{
    __shared__ __align__(16) float su0[ER*EC];
    __shared__ __align__(16) float su1[ER*EC];
    __shared__ __align__(16) float sv0[ER*EC];
    __shared__ __align__(16) float sv1[ER*EC];

    const int img = blockIdx.x;
    const int cs  = blockIdx.y;
    const int rb  = blockIdx.z;
    const int tid = threadIdx.x;
    const int er0 = rb*TILE_R - TT;   // ext-tile origin (may be <0)
    const int ec0 = cs*TILE_C - TT;

    const float* __restrict__ srcu = src + img*2*PLANE;
    const float* __restrict__ srcv = srcu + PLANE;

    // ---- stage extended tile of u,v into LDS buffer 0 (zeros outside image) ----
    #pragma unroll
    for (int k = 0; k < (ER*EC)/256; ++k) {
        int idx = tid + k*256;
        int r = idx / EC;
        int c = idx - r*EC;
        int gr = er0 + r, gc = ec0 + c;
        float uu = 0.f, vv = 0.f;
        if (gr >= 0 && gr < HH && gc >= 0 && gc < WW) {
            int q = gr*WW + gc;
            uu = srcu[q];
            vv = srcv[q];
        }
        su0[idx] = uu;
        sv0[idx] = vv;
    }

    // ---- per-thread geometry: 2 adjacent cols x RPT rows ----
    const int cp = tid % NCP;          // 0..39
    const int rg = tid / NCP;          // 0..6 (rg==6 -> idle in sweep)
    const bool active = (rg < NRG);
    const int r0   = rg * RPT;
    const int base = 2*cp;
    const int o0 = (cp == 0)     ? 0      : base - 2;  // clamped pair reads:
    const int o2 = (cp == NCP-1) ? EC - 4 : base + 2;  // garbage only feeds d=0 ring

    // ---- per-pixel update coefficients (registers, 5 x 16 px) ----
    float2 ca[RPT], cb[RPT], cc[RPT], cd[RPT], ce[RPT];
    {
        const float* __restrict__ xit = x + img*3*PLANE;
        const float* __restrict__ xix = xit + PLANE;
        const float* __restrict__ xiy = xix + PLANE;
        #pragma unroll
        for (int i = 0; i < RPT; ++i) {
            int gr = er0 + r0 + i;
            #pragma unroll
            for (int j = 0; j < 2; ++j) {
                int gc = ec0 + base + j;
                float A=0.f, B=0.f, C=0.f, D=0.f, E=0.f;
                if (active && gr >= 0 && gr < HH && gc >= 0 && gc < WW) {
                    int q = gr*WW + gc;
                    float it = xit[q], ix = xix[q], iy = xiy[q];
                    float rd = 1.0f / (1.0f + ix*ix + iy*iy);
                    const float s12 = 1.0f/12.0f;
                    A = (1.0f - ix*ix*rd) * s12;
                    B = (ix*iy*rd) * s12;
                    C = ix*it*rd;
                    D = (1.0f - iy*iy*rd) * s12;
                    E = iy*it*rd;
                }
                if (j == 0) { ca[i].x=A; cb[i].x=B; cc[i].x=C; cd[i].x=D; ce[i].x=E; }
                else        { ca[i].y=A; cb[i].y=B; cc[i].y=C; cd[i].y=D; ce[i].y=E; }
            }
        }
    }

    __syncthreads();

    // ---- T iterations fully in LDS (ping-pong), 1 barrier per iteration ----
    for (int s = 1; s <= niter; ++s) {
        const float* __restrict__ ru = ((s-1)&1) ? su1 : su0;
        const float* __restrict__ rv = ((s-1)&1) ? sv1 : sv0;
        float* __restrict__ wu = (s&1) ? su1 : su0;
        float* __restrict__ wv = (s&1) ? sv1 : sv0;
        if (active) {
            float2 huA, hvA, huB, hvB, cu, cv, dum;
            {
                int rm = (r0 == 0) ? 0 : r0 - 1;   // clamped: feeds only d=0 ring
                const float* pu = ru + rm*EC;
                const float* pv = rv + rm*EC;
                huA = hrow(pu, o0, base, o2, &dum);
                hvA = hrow(pv, o0, base, o2, &dum);
                pu = ru + r0*EC;
                pv = rv + r0*EC;
                huB = hrow(pu, o0, base, o2, &cu);
                hvB = hrow(pv, o0, base, o2, &cv);
            }
            #pragma unroll
            for (int i = 0; i < RPT; ++i) {
                int rr = r0 + i + 1;
                if (rr > ER-1) rr = ER-1;           // clamped: feeds only d=0 ring
                const float* pu = ru + rr*EC;
                const float* pv = rv + rr*EC;
                float2 cuN, cvN;
                float2 huN = hrow(pu, o0, base, o2, &cuN);
                float2 hvN = hrow(pv, o0, base, o2, &cvN);
                // tu = (sum of 3x3 with [1,2,1] weights) - 4*center  (=12*u_bar)
                float tux = fmaf(-4.f, cu.x, fmaf(2.f, huB.x, huA.x) + huN.x);
                float tuy = fmaf(-4.f, cu.y, fmaf(2.f, huB.y, huA.y) + huN.y);
                float tvx = fmaf(-4.f, cv.x, fmaf(2.f, hvB.x, hvA.x) + hvN.x);
                float tvy = fmaf(-4.f, cv.y, fmaf(2.f, hvB.y, hvA.y) + hvN.y);
                float2 un, vn;
                un.x = fmaf(ca[i].x, tux, -fmaf(cb[i].x, tvx, cc[i].x));
                un.y = fmaf(ca[i].y, tuy, -fmaf(cb[i].y, tvy, cc[i].y));
                vn.x = fmaf(cd[i].x, tvx, -fmaf(cb[i].x, tux, ce[i].x));
                vn.y = fmaf(cd[i].y, tvy, -fmaf(cb[i].y, tuy, ce[i].y));
                int wo = (r0 + i)*EC + base;
                *(float2*)(wu + wo) = un;
                *(float2*)(wv + wo) = vn;
                huA = huB; huB = huN; cu = cuN;
                hvA = hvB; hvB = hvN; cv = cvN;
            }
        }
        __syncthreads();
    }

    // ---- write inner tile to global ----
    {
        const float* fu = (niter & 1) ? su1 : su0;
        const float* fv = (niter & 1) ? sv1 : sv0;
        float* du = dst + img*2*PLANE;
        float* dv = du + PLANE;
        #pragma unroll
        for (int k = 0; k < (TILE_R*TILE_C)/256; ++k) {
            int idx = tid + k*256;
            int r = idx >> 6, c = idx & 63;
            int gr = rb*TILE_R + r, gc = cs*TILE_C + c;
            int lo = (r + TT)*EC + (c + TT);
            int q = gr*WW + gc;
            du[q] = fu[lo];
            dv[q] = fv[lo];
        }
    }
}

extern "C" void kernel_launch(void* const* d_in, const int* in_sizes, int n_in,
                              void* d_out, int out_size, void* d_ws, size_t ws_size,
                              hipStream_t stream) {
    const float* x   = (const float*)d_in[0];   // (8,3,256,256) fp32
    const float* est = (const float*)d_in[1];   // (8,2,256,256) fp32
    float* out = (float*)d_out;                 // (8,2,256,256) fp32
    float* wsA = (float*)d_ws;                  // 4 MB ping buffer

    dim3 grid(8, WW/TILE_C, HH/TILE_R);         // (img=8, colstrip=4, rowband=8) = 256 blocks
    dim3 blk(256);

    // 13 phases: 12 x 8 iters + 1 x 4 iters = 100.
    // dst alternates out/wsA so the final phase (p=12, even) lands in d_out.
    const float* s = est;
    for (int p = 0; p < 13; ++p) {
        float* d = ((p & 1) == 0) ? out : wsA;
        int niter = (p < 12) ? TT : 4;
        hs_phase<<<grid, blk, 0, stream>>>(x, s, d, niter);
        s = d;
    }
}